// Round 3
// baseline (6545.833 us; speedup 1.0000x reference)
//
#include <hip/hip_runtime.h>
#include <hip/hip_bf16.h>
#include <math.h>

typedef __hip_bfloat16 bf16;

#define EPSV 0.0001f

__device__ __forceinline__ float bfbits2f(unsigned int u16) {
    return __uint_as_float(u16 << 16);
}
__device__ __forceinline__ float bf2f(bf16 v) { return __bfloat162float(v); }

// ---------------------------------------------------------------------------
// Kernel 1: per-row reciprocal norm of the MP-normalized weights (fp32 in).
// rn[row] = 1 / (EPS*sqrt(768) + ||w[row,:]||)
// rows 0..2303 = w_qkv, rows 2304..3071 = w_proj. One block per row.
// ---------------------------------------------------------------------------
__global__ __launch_bounds__(256) void rownorm_kernel(
    const float* __restrict__ w_qkv, const float* __restrict__ w_proj,
    float* __restrict__ rn)
{
    const int row = blockIdx.x;
    const float* src = (row < 2304) ? (w_qkv + (size_t)row * 768)
                                    : (w_proj + (size_t)(row - 2304) * 768);
    const int tid = threadIdx.x;
    float ss = 0.f;
    #pragma unroll
    for (int j = 0; j < 3; j++) {
        const float v = src[tid + j * 256];
        ss += v * v;
    }
    #pragma unroll
    for (int off = 32; off > 0; off >>= 1) ss += __shfl_down(ss, off, 64);
    __shared__ float wsum[4];
    const int wid = tid >> 6, lane = tid & 63;
    if (lane == 0) wsum[wid] = ss;
    __syncthreads();
    if (tid == 0) {
        const float total = wsum[0] + wsum[1] + wsum[2] + wsum[3];
        rn[row] = 1.0f / (EPSV * 27.712812921102035f + sqrtf(total)); // sqrt(768)
    }
}

// ---------------------------------------------------------------------------
// Kernel 2: fused QKV GEMM + per-64ch normalize + RoPE -> Q,K,V (bf16 store).
// One block = (batch-frame b, group g=qkv*12+head, 64-pos tile). The 64 output
// rows of the tile are exactly the 64 channels of one head, so normalization
// over c=64 is block-local via LDS. All math fp32 (matches reference).
// Q/K/V layout: [bs][head][token=fr*256+pos][ch].
// ---------------------------------------------------------------------------
__global__ __launch_bounds__(256) void qkv_fused_kernel(
    const float* __restrict__ W,     // [2304][768] raw fp32 qkv weight
    const float* __restrict__ rn,    // [3072] row scales (first 2304 used)
    const float* __restrict__ X,     // [32][768][256] fp32
    bf16* __restrict__ Q, bf16* __restrict__ K, bf16* __restrict__ V)
{
    const int b  = blockIdx.z;           // 0..31  (= bs*16 + fr)
    const int g  = blockIdx.y;           // 0..35  (= qkv*12 + head)
    const int n0 = blockIdx.x * 64;      // position tile
    const int bs = b >> 4, fr = b & 15;
    const int qkv = g / 12, head = g % 12;
    const int m0 = g * 64;
    const float* Xb = X + (size_t)b * 768 * 256;

    __shared__ float As[16][64];
    __shared__ float Bs[16][64];
    __shared__ float tile[64][65];
    __shared__ float psum[4][64];

    const int tid = threadIdx.x;
    const int tx = tid & 15, ty = tid >> 4;
    const int ar = tid >> 2, ac = (tid & 3) * 4;
    const int bk = tid >> 4, bn = (tid & 15) * 4;
    const float rscale = rn[m0 + ar];

    float acc[4][4] = {};

    for (int k0 = 0; k0 < 768; k0 += 16) {
        const float4 av = *(const float4*)&W[(size_t)(m0 + ar) * 768 + k0 + ac];
        const float4 bv = *(const float4*)&Xb[(size_t)(k0 + bk) * 256 + n0 + bn];
        __syncthreads();
        As[ac + 0][ar] = av.x * rscale;
        As[ac + 1][ar] = av.y * rscale;
        As[ac + 2][ar] = av.z * rscale;
        As[ac + 3][ar] = av.w * rscale;
        Bs[bk][bn + 0] = bv.x;
        Bs[bk][bn + 1] = bv.y;
        Bs[bk][bn + 2] = bv.z;
        Bs[bk][bn + 3] = bv.w;
        __syncthreads();
        #pragma unroll
        for (int k = 0; k < 16; k++) {
            const float4 a4 = *(const float4*)&As[k][ty * 4];
            const float4 b4 = *(const float4*)&Bs[k][tx * 4];
            const float a[4] = {a4.x, a4.y, a4.z, a4.w};
            const float bb[4] = {b4.x, b4.y, b4.z, b4.w};
            #pragma unroll
            for (int i = 0; i < 4; i++)
                #pragma unroll
                for (int j = 0; j < 4; j++)
                    acc[i][j] = fmaf(a[i], bb[j], acc[i][j]);
        }
    }

    #pragma unroll
    for (int i = 0; i < 4; i++)
        #pragma unroll
        for (int j = 0; j < 4; j++)
            tile[ty * 4 + i][tx * 4 + j] = acc[i][j];
    __syncthreads();

    const int col = tid & 63, qtr = tid >> 6;
    float ss = 0.f;
    #pragma unroll
    for (int l = 0; l < 16; l++) {
        const float v = tile[qtr * 16 + l][col];
        ss += v * v;
    }
    psum[qtr][col] = ss;
    __syncthreads();
    const float total = psum[0][col] + psum[1][col] + psum[2][col] + psum[3][col];
    const float inv = 1.0f / (EPSV + sqrtf(total) * 0.125f);   // /(eps + n/sqrt(64))

    const int token = fr * 256 + n0 + col;
    const size_t base = (((size_t)bs * 12 + head) * 4096 + token) * 64;

    if (qkv == 2) {
        #pragma unroll
        for (int l = 0; l < 16; l++) {
            const int ch = qtr * 16 + l;
            V[base + ch] = __float2bfloat16(tile[ch][col] * inv);
        }
    } else {
        bf16* dst = (qkv == 0) ? Q : K;
        #pragma unroll
        for (int l = 0; l < 16; l++) {
            const int ch = qtr * 16 + l;
            const int j = ch & 31;
            // inv_freq = 10000^(-j/32) = exp2(-j * log2(10000)/32)
            const float invf = exp2f(-(float)j * 0.41524101186092029f);
            const float ang = (float)fr * invf;
            float sn, cs;
            sincosf(ang, &sn, &cs);
            const float n1 = tile[j][col] * inv;
            const float n2 = tile[j + 32][col] * inv;
            const float out = (ch < 32) ? (n1 * cs - n2 * sn) : (n2 * cs + n1 * sn);
            dst[base + ch] = __float2bfloat16(out);
        }
    }
}

// ---------------------------------------------------------------------------
// Kernel 3: block-causal flash attention (frame-granular mask -> whole frames
// visible, no intra-frame predication). One thread = one query row. K/V reads
// are wave-uniform (scalarizable). Online softmax per 32-key tile.
// Output scattered into spatial layout Osp[b][ch*12+head][pos] (bf16).
// ---------------------------------------------------------------------------
__global__ __launch_bounds__(256) void attn_kernel(
    const bf16* __restrict__ Q, const bf16* __restrict__ Kg,
    const bf16* __restrict__ Vg, bf16* __restrict__ Osp)
{
    const int qfr = blockIdx.x, head = blockIdx.y, bs = blockIdx.z;
    const int tid = threadIdx.x;
    const size_t hb = ((size_t)(bs * 12 + head)) * 4096 * 64;

    float q[64];
    {
        const unsigned int* qp = (const unsigned int*)&Q[hb + ((size_t)qfr * 256 + tid) * 64];
        #pragma unroll
        for (int c2 = 0; c2 < 32; c2++) {
            const unsigned int u = qp[c2];
            q[2 * c2]     = bfbits2f(u & 0xffffu) * 0.125f;  // fold 1/sqrt(64)
            q[2 * c2 + 1] = bfbits2f(u >> 16) * 0.125f;
        }
    }
    float o[64];
    #pragma unroll
    for (int ch = 0; ch < 64; ch++) o[ch] = 0.f;
    float M = -1e30f, L = 0.f;

    const int nk = (qfr + 1) * 256;
    for (int kt = 0; kt < nk; kt += 32) {
        float s[32];
        #pragma unroll 4
        for (int j = 0; j < 32; j++) {
            const unsigned int* kp = (const unsigned int*)&Kg[hb + (size_t)(kt + j) * 64];
            float acc = 0.f;
            #pragma unroll
            for (int c2 = 0; c2 < 32; c2++) {
                const unsigned int u = kp[c2];
                acc = fmaf(q[2 * c2], bfbits2f(u & 0xffffu), acc);
                acc = fmaf(q[2 * c2 + 1], bfbits2f(u >> 16), acc);
            }
            s[j] = acc;
        }
        float tm = M;
        #pragma unroll
        for (int j = 0; j < 32; j++) tm = fmaxf(tm, s[j]);
        const float rescale = expf(M - tm);
        float l2 = 0.f;
        #pragma unroll
        for (int j = 0; j < 32; j++) { s[j] = expf(s[j] - tm); l2 += s[j]; }
        L = L * rescale + l2;
        #pragma unroll
        for (int ch = 0; ch < 64; ch++) o[ch] *= rescale;
        #pragma unroll 4
        for (int j = 0; j < 32; j++) {
            const unsigned int* vp = (const unsigned int*)&Vg[hb + (size_t)(kt + j) * 64];
            const float p = s[j];
            #pragma unroll
            for (int c2 = 0; c2 < 32; c2++) {
                const unsigned int u = vp[c2];
                o[2 * c2]     = fmaf(p, bfbits2f(u & 0xffffu), o[2 * c2]);
                o[2 * c2 + 1] = fmaf(p, bfbits2f(u >> 16), o[2 * c2 + 1]);
            }
        }
        M = tm;
    }
    const float invL = 1.0f / L;
    const size_t ob = ((size_t)(bs * 16 + qfr) * 768) * 256 + tid;
    #pragma unroll
    for (int ch = 0; ch < 64; ch++)
        Osp[ob + (size_t)(ch * 12 + head) * 256] = __float2bfloat16(o[ch] * invL);
}

// ---------------------------------------------------------------------------
// Kernel 4: projection GEMM + residual mix epilogue (fp32 out).
// out = (0.7*x + 0.3*(wp @ Osp)) / sqrt(0.58)
// ---------------------------------------------------------------------------
__global__ __launch_bounds__(256) void gemm_proj_kernel(
    const float* __restrict__ Wp,   // [768][768] raw fp32 proj weight
    const float* __restrict__ rn,   // [3072], rows 2304.. are proj scales
    const bf16*  __restrict__ Bm,   // [32][768][256] Osp bf16
    const float* __restrict__ X,    // [32][768][256] fp32
    float* __restrict__ Out)        // [32][768][256] fp32
{
    const int b  = blockIdx.z;
    const int m0 = blockIdx.y * 64;
    const int n0 = blockIdx.x * 64;
    const bf16* Bb = Bm + (size_t)b * 768 * 256;

    __shared__ float As[16][64];
    __shared__ float Bs[16][64];

    const int tid = threadIdx.x;
    const int tx = tid & 15, ty = tid >> 4;
    const int ar = tid >> 2, ac = (tid & 3) * 4;
    const int bk = tid >> 4, bn = (tid & 15) * 4;
    const float rscale = rn[2304 + m0 + ar];

    float acc[4][4] = {};

    for (int k0 = 0; k0 < 768; k0 += 16) {
        const float4  av = *(const float4*)&Wp[(size_t)(m0 + ar) * 768 + k0 + ac];
        const ushort4 bw = *(const ushort4*)&Bb[(size_t)(k0 + bk) * 256 + n0 + bn];
        __syncthreads();
        As[ac + 0][ar] = av.x * rscale;
        As[ac + 1][ar] = av.y * rscale;
        As[ac + 2][ar] = av.z * rscale;
        As[ac + 3][ar] = av.w * rscale;
        Bs[bk][bn + 0] = bfbits2f(bw.x);
        Bs[bk][bn + 1] = bfbits2f(bw.y);
        Bs[bk][bn + 2] = bfbits2f(bw.z);
        Bs[bk][bn + 3] = bfbits2f(bw.w);
        __syncthreads();
        #pragma unroll
        for (int k = 0; k < 16; k++) {
            const float4 a4 = *(const float4*)&As[k][ty * 4];
            const float4 b4 = *(const float4*)&Bs[k][tx * 4];
            const float a[4] = {a4.x, a4.y, a4.z, a4.w};
            const float bb[4] = {b4.x, b4.y, b4.z, b4.w};
            #pragma unroll
            for (int i = 0; i < 4; i++)
                #pragma unroll
                for (int j = 0; j < 4; j++)
                    acc[i][j] = fmaf(a[i], bb[j], acc[i][j]);
        }
    }
    const float kMix = 1.3130643285972254f; // 1/sqrt(0.58)
    #pragma unroll
    for (int i = 0; i < 4; i++)
        #pragma unroll
        for (int j = 0; j < 4; j++) {
            const size_t idx = (size_t)b * 768 * 256 + (size_t)(m0 + ty * 4 + i) * 256 + n0 + tx * 4 + j;
            const float xv = X[idx];
            Out[idx] = (0.7f * xv + 0.3f * acc[i][j]) * kMix;
        }
}

// ---------------------------------------------------------------------------
extern "C" void kernel_launch(void* const* d_in, const int* in_sizes, int n_in,
                              void* d_out, int out_size, void* d_ws, size_t ws_size,
                              hipStream_t stream) {
    const float* x     = (const float*)d_in[0];
    const float* wqkv  = (const float*)d_in[1];
    const float* wproj = (const float*)d_in[2];
    float* out = (float*)d_out;

    // workspace layout (total ~50.3 MB)
    char* ws = (char*)d_ws;
    float* rn  = (float*)(ws + 0);          //     12,288 B
    bf16*  Q   = (bf16*)(ws + 16384);       // 12,582,912 B
    bf16*  K   = (bf16*)(ws + 12599296);    // 12,582,912 B
    bf16*  V   = (bf16*)(ws + 25182208);    // 12,582,912 B
    bf16*  Osp = (bf16*)(ws + 37765120);    // 12,582,912 B   (end 50,348,032)

    rownorm_kernel<<<3072, 256, 0, stream>>>(wqkv, wproj, rn);
    qkv_fused_kernel<<<dim3(4, 36, 32), 256, 0, stream>>>(wqkv, rn, x, Q, K, V);
    attn_kernel<<<dim3(16, 12, 2), 256, 0, stream>>>(Q, K, V, Osp);
    gemm_proj_kernel<<<dim3(4, 12, 32), 256, 0, stream>>>(wproj, rn, Osp, x, out);
}

// Round 4
// 832.965 us; speedup vs baseline: 7.8585x; 7.8585x over previous
//
#include <hip/hip_runtime.h>
#include <hip/hip_bf16.h>
#include <math.h>

typedef __hip_bfloat16 bf16;
typedef __attribute__((ext_vector_type(8))) short short8;
typedef __attribute__((ext_vector_type(4))) float f32x4;

#define EPSV 0.0001f

__device__ __forceinline__ float bfbits2f(unsigned int u16) {
    return __uint_as_float(u16 << 16);
}
__device__ __forceinline__ unsigned short f2bf(float f) {  // RNE bf16 bits
    unsigned int u = __float_as_uint(f);
    u += 0x7fff + ((u >> 16) & 1);
    return (unsigned short)(u >> 16);
}

// ---------------------------------------------------------------------------
// Kernel 1: per-row reciprocal norm of the MP-normalized weights (fp32 in).
// rn[row] = 1 / (EPS*sqrt(768) + ||w[row,:]||)
// ---------------------------------------------------------------------------
__global__ __launch_bounds__(256) void rownorm_kernel(
    const float* __restrict__ w_qkv, const float* __restrict__ w_proj,
    float* __restrict__ rn)
{
    const int row = blockIdx.x;
    const float* src = (row < 2304) ? (w_qkv + (size_t)row * 768)
                                    : (w_proj + (size_t)(row - 2304) * 768);
    const int tid = threadIdx.x;
    float ss = 0.f;
    #pragma unroll
    for (int j = 0; j < 3; j++) {
        const float v = src[tid + j * 256];
        ss += v * v;
    }
    #pragma unroll
    for (int off = 32; off > 0; off >>= 1) ss += __shfl_down(ss, off, 64);
    __shared__ float wsum[4];
    const int wid = tid >> 6, lane = tid & 63;
    if (lane == 0) wsum[wid] = ss;
    __syncthreads();
    if (tid == 0) {
        const float total = wsum[0] + wsum[1] + wsum[2] + wsum[3];
        rn[row] = 1.0f / (EPSV * 27.712812921102035f + sqrtf(total)); // sqrt(768)
    }
}

// ---------------------------------------------------------------------------
// Kernel 2: fused QKV GEMM + per-64ch normalize + RoPE.
// Q: [bs][head][token][ch] bf16, PRE-SCALED by 0.125 (folds 1/sqrt(c)).
// K: [bs][head][token][ch] bf16.
// V: [bs][head][ch][token] bf16 (TRANSPOSED for attention PV B-operand).
// ---------------------------------------------------------------------------
__global__ __launch_bounds__(256) void qkv_fused_kernel(
    const float* __restrict__ W,     // [2304][768]
    const float* __restrict__ rn,    // [3072]
    const float* __restrict__ X,     // [32][768][256]
    bf16* __restrict__ Q, bf16* __restrict__ K, bf16* __restrict__ Vt)
{
    const int b  = blockIdx.z;           // 0..31  (= bs*16 + fr)
    const int g  = blockIdx.y;           // 0..35  (= qkv*12 + head)
    const int n0 = blockIdx.x * 64;
    const int bs = b >> 4, fr = b & 15;
    const int qkv = g / 12, head = g % 12;
    const int m0 = g * 64;
    const float* Xb = X + (size_t)b * 768 * 256;

    __shared__ float As[16][64];
    __shared__ float Bs[16][64];
    __shared__ float tile[64][65];
    __shared__ float psum[4][64];

    const int tid = threadIdx.x;
    const int tx = tid & 15, ty = tid >> 4;
    const int ar = tid >> 2, ac = (tid & 3) * 4;
    const int bk = tid >> 4, bn = (tid & 15) * 4;
    const float rscale = rn[m0 + ar];

    float acc[4][4] = {};

    for (int k0 = 0; k0 < 768; k0 += 16) {
        const float4 av = *(const float4*)&W[(size_t)(m0 + ar) * 768 + k0 + ac];
        const float4 bv = *(const float4*)&Xb[(size_t)(k0 + bk) * 256 + n0 + bn];
        __syncthreads();
        As[ac + 0][ar] = av.x * rscale;
        As[ac + 1][ar] = av.y * rscale;
        As[ac + 2][ar] = av.z * rscale;
        As[ac + 3][ar] = av.w * rscale;
        Bs[bk][bn + 0] = bv.x;
        Bs[bk][bn + 1] = bv.y;
        Bs[bk][bn + 2] = bv.z;
        Bs[bk][bn + 3] = bv.w;
        __syncthreads();
        #pragma unroll
        for (int k = 0; k < 16; k++) {
            const float4 a4 = *(const float4*)&As[k][ty * 4];
            const float4 b4 = *(const float4*)&Bs[k][tx * 4];
            const float a[4] = {a4.x, a4.y, a4.z, a4.w};
            const float bb[4] = {b4.x, b4.y, b4.z, b4.w};
            #pragma unroll
            for (int i = 0; i < 4; i++)
                #pragma unroll
                for (int j = 0; j < 4; j++)
                    acc[i][j] = fmaf(a[i], bb[j], acc[i][j]);
        }
    }

    #pragma unroll
    for (int i = 0; i < 4; i++)
        #pragma unroll
        for (int j = 0; j < 4; j++)
            tile[ty * 4 + i][tx * 4 + j] = acc[i][j];
    __syncthreads();

    const int col = tid & 63, qtr = tid >> 6;
    float ss = 0.f;
    #pragma unroll
    for (int l = 0; l < 16; l++) {
        const float v = tile[qtr * 16 + l][col];
        ss += v * v;
    }
    psum[qtr][col] = ss;
    __syncthreads();
    const float total = psum[0][col] + psum[1][col] + psum[2][col] + psum[3][col];
    const float inv = 1.0f / (EPSV + sqrtf(total) * 0.125f);

    const int token = fr * 256 + n0 + col;

    if (qkv == 2) {
        const size_t vbase = ((size_t)(bs * 12 + head) * 64) * 4096 + token;
        #pragma unroll
        for (int l = 0; l < 16; l++) {
            const int ch = qtr * 16 + l;
            Vt[vbase + (size_t)ch * 4096] = __float2bfloat16(tile[ch][col] * inv);
        }
    } else {
        const size_t base = (((size_t)bs * 12 + head) * 4096 + token) * 64;
        bf16* dst = (qkv == 0) ? Q : K;
        const float post = (qkv == 0) ? 0.125f : 1.0f;  // fold 1/sqrt(c) into Q
        #pragma unroll
        for (int l = 0; l < 16; l++) {
            const int ch = qtr * 16 + l;
            const int j = ch & 31;
            const float invf = exp2f(-(float)j * 0.41524101186092029f);
            const float ang = (float)fr * invf;
            float sn, cs;
            sincosf(ang, &sn, &cs);
            const float n1 = tile[j][col] * inv;
            const float n2 = tile[j + 32][col] * inv;
            const float out = (ch < 32) ? (n1 * cs - n2 * sn) : (n2 * cs + n1 * sn);
            dst[base + ch] = __float2bfloat16(out * post);
        }
    }
}

// ---------------------------------------------------------------------------
// Kernel 3: MFMA flash attention, frame-causal.
// Block = (qfr, head, bs), 4 waves; wave w owns queries [w*64, w*64+64).
// S^T = K·Q^T so P-values land key-contiguous per lane -> b64 pack to LDS,
// read back as PV A-operand with b128. Fixed softmax max = 8 (|s|<=8 since
// q,k rows have norm ~8 and 1/8 scale folded into Q): no rescale, no max pass.
// ---------------------------------------------------------------------------
__global__ __launch_bounds__(256, 2) void attn_mfma_kernel(
    const bf16* __restrict__ Qg, const bf16* __restrict__ Kg,
    const bf16* __restrict__ Vtg, bf16* __restrict__ Osp)
{
    const int qfr = 15 - blockIdx.x;   // heavy blocks dispatch first
    const int head = blockIdx.y, bs = blockIdx.z;
    const int tid = threadIdx.x;
    const int w = tid >> 6, lane = tid & 63;
    const int l15 = lane & 15, quad = lane >> 4;
    const size_t hb = ((size_t)(bs * 12 + head)) * 4096 * 64;  // Q/K/Vt elem base

    __shared__ unsigned short Ks[64 * 72];
    __shared__ unsigned short Vs[64 * 72];
    __shared__ unsigned short Pw[4][64 * 72];

    const unsigned short* Qu = (const unsigned short*)Qg;
    const unsigned short* Ku = (const unsigned short*)Kg;
    const unsigned short* Vu = (const unsigned short*)Vtg;

    // Q fragments (B operand of S^T): Qf[ni][kk] = Q[16ni+l15][32kk + 8quad ..]
    short8 Qf[4][2];
    {
        const int qrow = qfr * 256 + w * 64 + l15;
        #pragma unroll
        for (int ni = 0; ni < 4; ni++)
            #pragma unroll
            for (int kk = 0; kk < 2; kk++)
                Qf[ni][kk] = *(const short8*)&Qu[hb + (size_t)(qrow + 16 * ni) * 64 + 32 * kk + 8 * quad];
    }

    f32x4 O[4][4];
    #pragma unroll
    for (int a = 0; a < 4; a++)
        #pragma unroll
        for (int c = 0; c < 4; c++)
            O[a][c] = (f32x4){0.f, 0.f, 0.f, 0.f};
    float lsum[4] = {0.f, 0.f, 0.f, 0.f};
    const f32x4 zf = (f32x4){0.f, 0.f, 0.f, 0.f};

    const int stage_row = tid >> 2;
    const int stage_off = (tid & 3) * 16;

    const int nk = (qfr + 1) * 256;
    for (int t0 = 0; t0 < nk; t0 += 64) {
        __syncthreads();   // prior chunk's LDS reads complete
        {
            const size_t kg = hb + (size_t)(t0 + stage_row) * 64 + stage_off;
            const size_t vg = hb + (size_t)stage_row * 4096 + t0 + stage_off;
            const short8 ka = *(const short8*)&Ku[kg];
            const short8 kb = *(const short8*)&Ku[kg + 8];
            const short8 va = *(const short8*)&Vu[vg];
            const short8 vb = *(const short8*)&Vu[vg + 8];
            *(short8*)&Ks[stage_row * 72 + stage_off] = ka;
            *(short8*)&Ks[stage_row * 72 + stage_off + 8] = kb;
            *(short8*)&Vs[stage_row * 72 + stage_off] = va;
            *(short8*)&Vs[stage_row * 72 + stage_off + 8] = vb;
        }
        __syncthreads();

        // S^T[key][query] = K · Q^T
        f32x4 St[4][4];
        #pragma unroll
        for (int mi = 0; mi < 4; mi++) {
            const short8 kf0 = *(const short8*)&Ks[(16 * mi + l15) * 72 + 8 * quad];
            const short8 kf1 = *(const short8*)&Ks[(16 * mi + l15) * 72 + 32 + 8 * quad];
            #pragma unroll
            for (int ni = 0; ni < 4; ni++) {
                f32x4 s = __builtin_amdgcn_mfma_f32_16x16x32_bf16(kf0, Qf[ni][0], zf, 0, 0, 0);
                St[mi][ni] = __builtin_amdgcn_mfma_f32_16x16x32_bf16(kf1, Qf[ni][1], s, 0, 0, 0);
            }
        }

        // P = exp(S^T - 8): lane holds keys {16mi+4quad+r} for query 16ni+l15.
        #pragma unroll
        for (int ni = 0; ni < 4; ni++) {
            #pragma unroll
            for (int mi = 0; mi < 4; mi++) {
                const f32x4 s = St[mi][ni];
                const float p0 = __expf(s[0] - 8.f);
                const float p1 = __expf(s[1] - 8.f);
                const float p2 = __expf(s[2] - 8.f);
                const float p3 = __expf(s[3] - 8.f);
                lsum[ni] += (p0 + p1) + (p2 + p3);
                uint2 d;
                d.x = (unsigned int)f2bf(p0) | ((unsigned int)f2bf(p1) << 16);
                d.y = (unsigned int)f2bf(p2) | ((unsigned int)f2bf(p3) << 16);
                *(uint2*)&Pw[w][(16 * ni + l15) * 72 + 16 * mi + 4 * quad] = d;
            }
        }

        // PV: O[q][c] += P·V  (A=P from Pw, B=V from Vs)
        short8 Pf[4][2];
        #pragma unroll
        for (int mq = 0; mq < 4; mq++)
            #pragma unroll
            for (int ks = 0; ks < 2; ks++)
                Pf[mq][ks] = *(const short8*)&Pw[w][(16 * mq + l15) * 72 + 32 * ks + 8 * quad];
        #pragma unroll
        for (int ci = 0; ci < 4; ci++) {
            const short8 vf0 = *(const short8*)&Vs[(16 * ci + l15) * 72 + 8 * quad];
            const short8 vf1 = *(const short8*)&Vs[(16 * ci + l15) * 72 + 32 + 8 * quad];
            #pragma unroll
            for (int mq = 0; mq < 4; mq++) {
                O[mq][ci] = __builtin_amdgcn_mfma_f32_16x16x32_bf16(Pf[mq][0], vf0, O[mq][ci], 0, 0, 0);
                O[mq][ci] = __builtin_amdgcn_mfma_f32_16x16x32_bf16(Pf[mq][1], vf1, O[mq][ci], 0, 0, 0);
            }
        }
    }

    // finish l (cross-quad) and invert
    #pragma unroll
    for (int ni = 0; ni < 4; ni++) {
        lsum[ni] += __shfl_xor(lsum[ni], 16, 64);
        lsum[ni] += __shfl_xor(lsum[ni], 32, 64);
        lsum[ni] = 1.0f / lsum[ni];
    }

    // epilogue: O row = 16mq + 4quad + r (query), col = 16ci + l15 (channel)
    const size_t ob = (((size_t)(bs * 16 + qfr)) * 768 + head) * 256 + w * 64;
    #pragma unroll
    for (int mq = 0; mq < 4; mq++) {
        #pragma unroll
        for (int r = 0; r < 4; r++) {
            const float inv = __shfl(lsum[mq], quad * 4 + r, 64);
            const int pos = 16 * mq + 4 * quad + r;
            #pragma unroll
            for (int ci = 0; ci < 4; ci++) {
                const int chG = 16 * ci + l15;
                Osp[ob + (size_t)chG * 12 * 256 + pos] = __float2bfloat16(O[mq][ci][r] * inv);
            }
        }
    }
}

// ---------------------------------------------------------------------------
// Kernel 4: projection GEMM + residual mix epilogue (fp32 out).
// out = (0.7*x + 0.3*(wp @ Osp)) / sqrt(0.58)
// ---------------------------------------------------------------------------
__global__ __launch_bounds__(256) void gemm_proj_kernel(
    const float* __restrict__ Wp,   // [768][768]
    const float* __restrict__ rn,   // rows 2304.. are proj scales
    const bf16*  __restrict__ Bm,   // [32][768][256] Osp bf16
    const float* __restrict__ X,    // [32][768][256]
    float* __restrict__ Out)
{
    const int b  = blockIdx.z;
    const int m0 = blockIdx.y * 64;
    const int n0 = blockIdx.x * 64;
    const bf16* Bb = Bm + (size_t)b * 768 * 256;

    __shared__ float As[16][64];
    __shared__ float Bs[16][64];

    const int tid = threadIdx.x;
    const int tx = tid & 15, ty = tid >> 4;
    const int ar = tid >> 2, ac = (tid & 3) * 4;
    const int bk = tid >> 4, bn = (tid & 15) * 4;
    const float rscale = rn[2304 + m0 + ar];

    float acc[4][4] = {};

    for (int k0 = 0; k0 < 768; k0 += 16) {
        const float4  av = *(const float4*)&Wp[(size_t)(m0 + ar) * 768 + k0 + ac];
        const ushort4 bw = *(const ushort4*)&Bb[(size_t)(k0 + bk) * 256 + n0 + bn];
        __syncthreads();
        As[ac + 0][ar] = av.x * rscale;
        As[ac + 1][ar] = av.y * rscale;
        As[ac + 2][ar] = av.z * rscale;
        As[ac + 3][ar] = av.w * rscale;
        Bs[bk][bn + 0] = bfbits2f(bw.x);
        Bs[bk][bn + 1] = bfbits2f(bw.y);
        Bs[bk][bn + 2] = bfbits2f(bw.z);
        Bs[bk][bn + 3] = bfbits2f(bw.w);
        __syncthreads();
        #pragma unroll
        for (int k = 0; k < 16; k++) {
            const float4 a4 = *(const float4*)&As[k][ty * 4];
            const float4 b4 = *(const float4*)&Bs[k][tx * 4];
            const float a[4] = {a4.x, a4.y, a4.z, a4.w};
            const float bb[4] = {b4.x, b4.y, b4.z, b4.w};
            #pragma unroll
            for (int i = 0; i < 4; i++)
                #pragma unroll
                for (int j = 0; j < 4; j++)
                    acc[i][j] = fmaf(a[i], bb[j], acc[i][j]);
        }
    }
    const float kMix = 1.3130643285972254f; // 1/sqrt(0.58)
    #pragma unroll
    for (int i = 0; i < 4; i++)
        #pragma unroll
        for (int j = 0; j < 4; j++) {
            const size_t idx = (size_t)b * 768 * 256 + (size_t)(m0 + ty * 4 + i) * 256 + n0 + tx * 4 + j;
            const float xv = X[idx];
            Out[idx] = (0.7f * xv + 0.3f * acc[i][j]) * kMix;
        }
}

// ---------------------------------------------------------------------------
extern "C" void kernel_launch(void* const* d_in, const int* in_sizes, int n_in,
                              void* d_out, int out_size, void* d_ws, size_t ws_size,
                              hipStream_t stream) {
    const float* x     = (const float*)d_in[0];
    const float* wqkv  = (const float*)d_in[1];
    const float* wproj = (const float*)d_in[2];
    float* out = (float*)d_out;

    char* ws = (char*)d_ws;
    float* rn  = (float*)(ws + 0);          //     12,288 B
    bf16*  Q   = (bf16*)(ws + 16384);       // 12,582,912 B
    bf16*  K   = (bf16*)(ws + 12599296);    // 12,582,912 B
    bf16*  Vt  = (bf16*)(ws + 25182208);    // 12,582,912 B  ([bs][head][ch][token])
    bf16*  Osp = (bf16*)(ws + 37765120);    // 12,582,912 B

    rownorm_kernel<<<3072, 256, 0, stream>>>(wqkv, wproj, rn);
    qkv_fused_kernel<<<dim3(4, 36, 32), 256, 0, stream>>>(wqkv, rn, x, Q, K, Vt);
    attn_mfma_kernel<<<dim3(16, 12, 2), 256, 0, stream>>>(Q, K, Vt, Osp);
    gemm_proj_kernel<<<dim3(4, 12, 32), 256, 0, stream>>>(wproj, rn, Osp, x, out);
}

// Round 5
// 573.858 us; speedup vs baseline: 11.4067x; 1.4515x over previous
//
#include <hip/hip_runtime.h>
#include <hip/hip_bf16.h>
#include <math.h>

typedef __hip_bfloat16 bf16;
typedef __attribute__((ext_vector_type(8))) short short8;
typedef __attribute__((ext_vector_type(4))) float f32x4;

#define EPSV 0.0001f

__device__ __forceinline__ float bfbits2f(unsigned int u16) {
    return __uint_as_float(u16 << 16);
}
__device__ __forceinline__ unsigned short f2bf(float f) {  // RNE bf16 bits
    unsigned int u = __float_as_uint(f);
    u += 0x7fff + ((u >> 16) & 1);
    return (unsigned short)(u >> 16);
}

// ---------------------------------------------------------------------------
// Kernel 1: weight row-norm + cast to bf16 with scale folded in.
// w_final[row] = w[row] / (EPS*sqrt(768) + ||w[row]||), stored bf16.
// rows 0..2303 -> Wqb, 2304..3071 -> Wpb. One block per row.
// ---------------------------------------------------------------------------
__global__ __launch_bounds__(256) void rownorm_cast_kernel(
    const float* __restrict__ w_qkv, const float* __restrict__ w_proj,
    unsigned short* __restrict__ Wqb, unsigned short* __restrict__ Wpb)
{
    const int row = blockIdx.x;
    const float* src;
    unsigned short* dst;
    if (row < 2304) { src = w_qkv + (size_t)row * 768;           dst = Wqb + (size_t)row * 768; }
    else            { src = w_proj + (size_t)(row - 2304) * 768; dst = Wpb + (size_t)(row - 2304) * 768; }

    const int tid = threadIdx.x;
    float v[3];
    float ss = 0.f;
    #pragma unroll
    for (int j = 0; j < 3; j++) {
        v[j] = src[tid + j * 256];
        ss += v[j] * v[j];
    }
    #pragma unroll
    for (int off = 32; off > 0; off >>= 1) ss += __shfl_down(ss, off, 64);
    __shared__ float wsum[4];
    if ((tid & 63) == 0) wsum[tid >> 6] = ss;
    __syncthreads();
    const float total = wsum[0] + wsum[1] + wsum[2] + wsum[3];
    const float scale = 1.0f / (EPSV * 27.712812921102035f + sqrtf(total)); // sqrt(768)
    #pragma unroll
    for (int j = 0; j < 3; j++) dst[tid + j * 256] = f2bf(v[j] * scale);
}

// ---------------------------------------------------------------------------
// Kernel 2: X [32][768][256] fp32 -> XbT [32][256][768] bf16 (transposed).
// Block = (ctile, b); thread owns one pos; reads coalesced across lanes.
// ---------------------------------------------------------------------------
__global__ __launch_bounds__(256) void cast_x_kernel(
    const float* __restrict__ X, unsigned short* __restrict__ XbT)
{
    const int c0 = blockIdx.x * 64;
    const int b  = blockIdx.y;
    const int pos = threadIdx.x;
    const float* src = X + ((size_t)b * 768 + c0) * 256 + pos;
    unsigned short* dst = XbT + ((size_t)b * 256 + pos) * 768 + c0;
    #pragma unroll
    for (int cc = 0; cc < 8; cc++) {
        short8 t;
        #pragma unroll
        for (int j = 0; j < 8; j++)
            t[j] = (short)f2bf(src[(size_t)(cc * 8 + j) * 256]);
        *(short8*)&dst[cc * 8] = t;
    }
}

// ---------------------------------------------------------------------------
// Kernel 3: QKV GEMM (MFMA bf16) + fused in-register normalize + RoPE.
// Block = (64-pos tile, group g=qkv*12+head, batch-frame b). Wave owns 16
// positions; acc C-layout: lane holds 16 channels of ONE position -> ssq
// reduction is 2 xor-shuffles; RoPE pairs (j, j+32) = (acc[mi], acc[mi+2]).
// Q: [bs][head][token][ch] bf16 pre-scaled 0.125; K same unscaled;
// Vt: [bs][head][ch][token] bf16.
// ---------------------------------------------------------------------------
__global__ __launch_bounds__(256) void qkv_mfma_kernel(
    const unsigned short* __restrict__ Wqb,  // [2304][768] bf16, scale folded
    const unsigned short* __restrict__ XbT,  // [32][256][768] bf16
    bf16* __restrict__ Q, bf16* __restrict__ K, bf16* __restrict__ Vt)
{
    const int n0 = blockIdx.x * 64;
    const int g  = blockIdx.y;
    const int b  = blockIdx.z;
    const int bs = b >> 4, fr = b & 15;
    const int qkv = g / 12, head = g % 12;
    const int m0 = g * 64;

    const int tid = threadIdx.x;
    const int w = tid >> 6, lane = tid & 63;
    const int l15 = lane & 15, quad = lane >> 4;

    __shared__ unsigned short Bs[64 * 72];

    const unsigned short* Arow = Wqb + (size_t)m0 * 768;
    const unsigned short* Bsrc = XbT + ((size_t)b * 256 + n0) * 768;

    f32x4 acc[4];
    #pragma unroll
    for (int mi = 0; mi < 4; mi++) acc[mi] = (f32x4){0.f, 0.f, 0.f, 0.f};

    const int srow = tid >> 2, soff = (tid & 3) * 16;

    for (int k0 = 0; k0 < 768; k0 += 64) {
        short8 af[4][2];
        #pragma unroll
        for (int mi = 0; mi < 4; mi++)
            #pragma unroll
            for (int kk = 0; kk < 2; kk++)
                af[mi][kk] = *(const short8*)&Arow[(size_t)(16 * mi + l15) * 768 + k0 + 32 * kk + 8 * quad];
        const short8 s0 = *(const short8*)&Bsrc[(size_t)srow * 768 + k0 + soff];
        const short8 s1 = *(const short8*)&Bsrc[(size_t)srow * 768 + k0 + soff + 8];
        __syncthreads();
        *(short8*)&Bs[srow * 72 + soff] = s0;
        *(short8*)&Bs[srow * 72 + soff + 8] = s1;
        __syncthreads();
        #pragma unroll
        for (int kk = 0; kk < 2; kk++) {
            const short8 bfrag = *(const short8*)&Bs[(16 * w + l15) * 72 + 32 * kk + 8 * quad];
            #pragma unroll
            for (int mi = 0; mi < 4; mi++)
                acc[mi] = __builtin_amdgcn_mfma_f32_16x16x32_bf16(af[mi][kk], bfrag, acc[mi], 0, 0, 0);
        }
    }

    // in-register normalization over 64 channels (this lane's position)
    float ssq = 0.f;
    #pragma unroll
    for (int mi = 0; mi < 4; mi++)
        #pragma unroll
        for (int r = 0; r < 4; r++)
            ssq = fmaf(acc[mi][r], acc[mi][r], ssq);
    ssq += __shfl_xor(ssq, 16, 64);
    ssq += __shfl_xor(ssq, 32, 64);
    const float inv = 1.0f / (EPSV + sqrtf(ssq) * 0.125f);

    const int token = fr * 256 + n0 + 16 * w + l15;

    if (qkv == 2) {
        const size_t vbase = ((size_t)(bs * 12 + head) * 64) * 4096 + token;
        #pragma unroll
        for (int mi = 0; mi < 4; mi++)
            #pragma unroll
            for (int r = 0; r < 4; r++)
                Vt[vbase + (size_t)(16 * mi + 4 * quad + r) * 4096] =
                    __float2bfloat16(acc[mi][r] * inv);
    } else {
        unsigned short* dst = (unsigned short*)((qkv == 0) ? Q : K);
        const float post = (qkv == 0) ? 0.125f : 1.0f;  // fold 1/sqrt(c) into Q
        const size_t base = (((size_t)(bs * 12 + head)) * 4096 + token) * 64;
        #pragma unroll
        for (int mi = 0; mi < 2; mi++) {
            unsigned int lo[2], hi[2];
            #pragma unroll
            for (int r = 0; r < 4; r++) {
                const int j = 16 * mi + 4 * quad + r;
                const float n1 = acc[mi][r] * inv;
                const float n2 = acc[mi + 2][r] * inv;
                const float ang = (float)fr * exp2f(-(float)j * 0.41524101186092029f);
                float sn, cs;
                __sincosf(ang, &sn, &cs);
                const unsigned short o1 = f2bf((n1 * cs - n2 * sn) * post);
                const unsigned short o2 = f2bf((n2 * cs + n1 * sn) * post);
                if (r < 2) { if (r == 0) { lo[0] = o1; hi[0] = o2; } else { lo[0] |= (unsigned int)o1 << 16; hi[0] |= (unsigned int)o2 << 16; } }
                else       { if (r == 2) { lo[1] = o1; hi[1] = o2; } else { lo[1] |= (unsigned int)o1 << 16; hi[1] |= (unsigned int)o2 << 16; } }
            }
            *(uint2*)&dst[base + 16 * mi + 4 * quad]      = make_uint2(lo[0], lo[1]);
            *(uint2*)&dst[base + 32 + 16 * mi + 4 * quad] = make_uint2(hi[0], hi[1]);
        }
    }
}

// ---------------------------------------------------------------------------
// Kernel 4: MFMA flash attention, frame-causal (unchanged core).
// Epilogue now writes OspT[b][pos][chan] (chan = ch*12+head) for the proj
// GEMM's k-contiguous B-fragments.
// ---------------------------------------------------------------------------
__global__ __launch_bounds__(256, 2) void attn_mfma_kernel(
    const bf16* __restrict__ Qg, const bf16* __restrict__ Kg,
    const bf16* __restrict__ Vtg, unsigned short* __restrict__ OspT)
{
    const int qfr = 15 - blockIdx.x;   // heavy blocks dispatch first
    const int head = blockIdx.y, bs = blockIdx.z;
    const int tid = threadIdx.x;
    const int w = tid >> 6, lane = tid & 63;
    const int l15 = lane & 15, quad = lane >> 4;
    const size_t hb = ((size_t)(bs * 12 + head)) * 4096 * 64;

    __shared__ unsigned short Ks[64 * 72];
    __shared__ unsigned short Vs[64 * 72];
    __shared__ unsigned short Pw[4][64 * 72];

    const unsigned short* Qu = (const unsigned short*)Qg;
    const unsigned short* Ku = (const unsigned short*)Kg;
    const unsigned short* Vu = (const unsigned short*)Vtg;

    short8 Qf[4][2];
    {
        const int qrow = qfr * 256 + w * 64 + l15;
        #pragma unroll
        for (int ni = 0; ni < 4; ni++)
            #pragma unroll
            for (int kk = 0; kk < 2; kk++)
                Qf[ni][kk] = *(const short8*)&Qu[hb + (size_t)(qrow + 16 * ni) * 64 + 32 * kk + 8 * quad];
    }

    f32x4 O[4][4];
    #pragma unroll
    for (int a = 0; a < 4; a++)
        #pragma unroll
        for (int c = 0; c < 4; c++)
            O[a][c] = (f32x4){0.f, 0.f, 0.f, 0.f};
    float lsum[4] = {0.f, 0.f, 0.f, 0.f};
    const f32x4 zf = (f32x4){0.f, 0.f, 0.f, 0.f};

    const int stage_row = tid >> 2;
    const int stage_off = (tid & 3) * 16;

    const int nk = (qfr + 1) * 256;
    for (int t0 = 0; t0 < nk; t0 += 64) {
        __syncthreads();
        {
            const size_t kg = hb + (size_t)(t0 + stage_row) * 64 + stage_off;
            const size_t vg = hb + (size_t)stage_row * 4096 + t0 + stage_off;
            const short8 ka = *(const short8*)&Ku[kg];
            const short8 kb = *(const short8*)&Ku[kg + 8];
            const short8 va = *(const short8*)&Vu[vg];
            const short8 vb = *(const short8*)&Vu[vg + 8];
            *(short8*)&Ks[stage_row * 72 + stage_off] = ka;
            *(short8*)&Ks[stage_row * 72 + stage_off + 8] = kb;
            *(short8*)&Vs[stage_row * 72 + stage_off] = va;
            *(short8*)&Vs[stage_row * 72 + stage_off + 8] = vb;
        }
        __syncthreads();

        f32x4 St[4][4];
        #pragma unroll
        for (int mi = 0; mi < 4; mi++) {
            const short8 kf0 = *(const short8*)&Ks[(16 * mi + l15) * 72 + 8 * quad];
            const short8 kf1 = *(const short8*)&Ks[(16 * mi + l15) * 72 + 32 + 8 * quad];
            #pragma unroll
            for (int ni = 0; ni < 4; ni++) {
                f32x4 s = __builtin_amdgcn_mfma_f32_16x16x32_bf16(kf0, Qf[ni][0], zf, 0, 0, 0);
                St[mi][ni] = __builtin_amdgcn_mfma_f32_16x16x32_bf16(kf1, Qf[ni][1], s, 0, 0, 0);
            }
        }

        #pragma unroll
        for (int ni = 0; ni < 4; ni++) {
            #pragma unroll
            for (int mi = 0; mi < 4; mi++) {
                const f32x4 s = St[mi][ni];
                const float p0 = __expf(s[0] - 8.f);
                const float p1 = __expf(s[1] - 8.f);
                const float p2 = __expf(s[2] - 8.f);
                const float p3 = __expf(s[3] - 8.f);
                lsum[ni] += (p0 + p1) + (p2 + p3);
                uint2 d;
                d.x = (unsigned int)f2bf(p0) | ((unsigned int)f2bf(p1) << 16);
                d.y = (unsigned int)f2bf(p2) | ((unsigned int)f2bf(p3) << 16);
                *(uint2*)&Pw[w][(16 * ni + l15) * 72 + 16 * mi + 4 * quad] = d;
            }
        }

        short8 Pf[4][2];
        #pragma unroll
        for (int mq = 0; mq < 4; mq++)
            #pragma unroll
            for (int ks = 0; ks < 2; ks++)
                Pf[mq][ks] = *(const short8*)&Pw[w][(16 * mq + l15) * 72 + 32 * ks + 8 * quad];
        #pragma unroll
        for (int ci = 0; ci < 4; ci++) {
            const short8 vf0 = *(const short8*)&Vs[(16 * ci + l15) * 72 + 8 * quad];
            const short8 vf1 = *(const short8*)&Vs[(16 * ci + l15) * 72 + 32 + 8 * quad];
            #pragma unroll
            for (int mq = 0; mq < 4; mq++) {
                O[mq][ci] = __builtin_amdgcn_mfma_f32_16x16x32_bf16(Pf[mq][0], vf0, O[mq][ci], 0, 0, 0);
                O[mq][ci] = __builtin_amdgcn_mfma_f32_16x16x32_bf16(Pf[mq][1], vf1, O[mq][ci], 0, 0, 0);
            }
        }
    }

    #pragma unroll
    for (int ni = 0; ni < 4; ni++) {
        lsum[ni] += __shfl_xor(lsum[ni], 16, 64);
        lsum[ni] += __shfl_xor(lsum[ni], 32, 64);
        lsum[ni] = 1.0f / lsum[ni];
    }

    const size_t ob = ((size_t)(bs * 16 + qfr)) * 196608;   // 256*768
    #pragma unroll
    for (int mq = 0; mq < 4; mq++) {
        #pragma unroll
        for (int r = 0; r < 4; r++) {
            const float inv = __shfl(lsum[mq], quad * 4 + r, 64);
            const int pos = w * 64 + 16 * mq + 4 * quad + r;
            #pragma unroll
            for (int ci = 0; ci < 4; ci++) {
                const int chan = (16 * ci + l15) * 12 + head;
                OspT[ob + (size_t)pos * 768 + chan] = f2bf(O[mq][ci][r] * inv);
            }
        }
    }
}

// ---------------------------------------------------------------------------
// Kernel 5: projection GEMM (MFMA bf16) + residual mix epilogue (fp32 out).
// out = (0.7*x + 0.3*(wp @ o)) / sqrt(0.58)
// ---------------------------------------------------------------------------
__global__ __launch_bounds__(256) void proj_mfma_kernel(
    const unsigned short* __restrict__ Wpb,   // [768][768] bf16, scale folded
    const unsigned short* __restrict__ OspT,  // [32][256][768] bf16
    const float* __restrict__ X,
    float* __restrict__ Out)
{
    const int n0 = blockIdx.x * 64;
    const int m0 = blockIdx.y * 64;
    const int b  = blockIdx.z;

    const int tid = threadIdx.x;
    const int w = tid >> 6, lane = tid & 63;
    const int l15 = lane & 15, quad = lane >> 4;

    __shared__ unsigned short Bs[64 * 72];

    const unsigned short* Arow = Wpb + (size_t)m0 * 768;
    const unsigned short* Bsrc = OspT + ((size_t)b * 256 + n0) * 768;

    f32x4 acc[4];
    #pragma unroll
    for (int mi = 0; mi < 4; mi++) acc[mi] = (f32x4){0.f, 0.f, 0.f, 0.f};

    const int srow = tid >> 2, soff = (tid & 3) * 16;

    for (int k0 = 0; k0 < 768; k0 += 64) {
        short8 af[4][2];
        #pragma unroll
        for (int mi = 0; mi < 4; mi++)
            #pragma unroll
            for (int kk = 0; kk < 2; kk++)
                af[mi][kk] = *(const short8*)&Arow[(size_t)(16 * mi + l15) * 768 + k0 + 32 * kk + 8 * quad];
        const short8 s0 = *(const short8*)&Bsrc[(size_t)srow * 768 + k0 + soff];
        const short8 s1 = *(const short8*)&Bsrc[(size_t)srow * 768 + k0 + soff + 8];
        __syncthreads();
        *(short8*)&Bs[srow * 72 + soff] = s0;
        *(short8*)&Bs[srow * 72 + soff + 8] = s1;
        __syncthreads();
        #pragma unroll
        for (int kk = 0; kk < 2; kk++) {
            const short8 bfrag = *(const short8*)&Bs[(16 * w + l15) * 72 + 32 * kk + 8 * quad];
            #pragma unroll
            for (int mi = 0; mi < 4; mi++)
                acc[mi] = __builtin_amdgcn_mfma_f32_16x16x32_bf16(af[mi][kk], bfrag, acc[mi], 0, 0, 0);
        }
    }

    const float kMix = 1.3130643285972254f; // 1/sqrt(0.58)
    const int n = n0 + 16 * w + l15;
    #pragma unroll
    for (int mi = 0; mi < 4; mi++) {
        #pragma unroll
        for (int r = 0; r < 4; r++) {
            const int m = m0 + 16 * mi + 4 * quad + r;
            const size_t idx = (size_t)b * 196608 + (size_t)m * 256 + n;
            Out[idx] = (0.7f * X[idx] + 0.3f * acc[mi][r]) * kMix;
        }
    }
}

// ---------------------------------------------------------------------------
extern "C" void kernel_launch(void* const* d_in, const int* in_sizes, int n_in,
                              void* d_out, int out_size, void* d_ws, size_t ws_size,
                              hipStream_t stream) {
    const float* x     = (const float*)d_in[0];
    const float* wqkv  = (const float*)d_in[1];
    const float* wproj = (const float*)d_in[2];
    float* out = (float*)d_out;

    // workspace layout (~55 MB). OspT aliases XbT (dead after qkv_mfma).
    char* ws = (char*)d_ws;
    unsigned short* Wqb  = (unsigned short*)(ws + 0);          //  3,538,944 B
    unsigned short* Wpb  = (unsigned short*)(ws + 3538944);    //  1,179,648 B
    unsigned short* XbT  = (unsigned short*)(ws + 4718592);    // 12,582,912 B
    unsigned short* OspT = XbT;                                // alias
    bf16*  Q   = (bf16*)(ws + 17301504);                       // 12,582,912 B
    bf16*  K   = (bf16*)(ws + 29884416);                       // 12,582,912 B
    bf16*  Vt  = (bf16*)(ws + 42467328);                       // 12,582,912 B -> 55,050,240

    rownorm_cast_kernel<<<3072, 256, 0, stream>>>(wqkv, wproj, Wqb, Wpb);
    cast_x_kernel<<<dim3(12, 32), 256, 0, stream>>>(x, XbT);
    qkv_mfma_kernel<<<dim3(4, 36, 32), 256, 0, stream>>>(Wqb, XbT, Q, K, Vt);
    attn_mfma_kernel<<<dim3(16, 12, 2), 256, 0, stream>>>(Q, K, Vt, OspT);
    proj_mfma_kernel<<<dim3(4, 12, 32), 256, 0, stream>>>(Wpb, OspT, x, out);
}

// Round 6
// 510.373 us; speedup vs baseline: 12.8256x; 1.1244x over previous
//
#include <hip/hip_runtime.h>
#include <hip/hip_bf16.h>
#include <math.h>

typedef __hip_bfloat16 bf16;
typedef __attribute__((ext_vector_type(8))) short short8;
typedef __attribute__((ext_vector_type(4))) float f32x4;

#define EPSV 0.0001f

__device__ __forceinline__ float bfbits2f(unsigned int u16) {
    return __uint_as_float(u16 << 16);
}
__device__ __forceinline__ unsigned short f2bf(float f) {  // RNE bf16 bits
    unsigned int u = __float_as_uint(f);
    u += 0x7fff + ((u >> 16) & 1);
    return (unsigned short)(u >> 16);
}

// ---------------------------------------------------------------------------
// Kernel 1: weight row-norm + cast to bf16 with scale folded in.
// ---------------------------------------------------------------------------
__global__ __launch_bounds__(256) void rownorm_cast_kernel(
    const float* __restrict__ w_qkv, const float* __restrict__ w_proj,
    unsigned short* __restrict__ Wqb, unsigned short* __restrict__ Wpb)
{
    const int row = blockIdx.x;
    const float* src;
    unsigned short* dst;
    if (row < 2304) { src = w_qkv + (size_t)row * 768;           dst = Wqb + (size_t)row * 768; }
    else            { src = w_proj + (size_t)(row - 2304) * 768; dst = Wpb + (size_t)(row - 2304) * 768; }

    const int tid = threadIdx.x;
    float v[3];
    float ss = 0.f;
    #pragma unroll
    for (int j = 0; j < 3; j++) {
        v[j] = src[tid + j * 256];
        ss += v[j] * v[j];
    }
    #pragma unroll
    for (int off = 32; off > 0; off >>= 1) ss += __shfl_down(ss, off, 64);
    __shared__ float wsum[4];
    if ((tid & 63) == 0) wsum[tid >> 6] = ss;
    __syncthreads();
    const float total = wsum[0] + wsum[1] + wsum[2] + wsum[3];
    const float scale = 1.0f / (EPSV * 27.712812921102035f + sqrtf(total)); // sqrt(768)
    #pragma unroll
    for (int j = 0; j < 3; j++) dst[tid + j * 256] = f2bf(v[j] * scale);
}

// ---------------------------------------------------------------------------
// Kernel 2: X [32][768][256] fp32 -> XbT [32][256][768] bf16 (transposed).
// ---------------------------------------------------------------------------
__global__ __launch_bounds__(256) void cast_x_kernel(
    const float* __restrict__ X, unsigned short* __restrict__ XbT)
{
    const int c0 = blockIdx.x * 64;
    const int b  = blockIdx.y;
    const int pos = threadIdx.x;
    const float* src = X + ((size_t)b * 768 + c0) * 256 + pos;
    unsigned short* dst = XbT + ((size_t)b * 256 + pos) * 768 + c0;
    #pragma unroll
    for (int cc = 0; cc < 8; cc++) {
        short8 t;
        #pragma unroll
        for (int j = 0; j < 8; j++)
            t[j] = (short)f2bf(src[(size_t)(cc * 8 + j) * 256]);
        *(short8*)&dst[cc * 8] = t;
    }
}

// ---------------------------------------------------------------------------
// Kernel 3: QKV GEMM (MFMA bf16) + fused in-register normalize + RoPE.
// ---------------------------------------------------------------------------
__global__ __launch_bounds__(256) void qkv_mfma_kernel(
    const unsigned short* __restrict__ Wqb,  // [2304][768] bf16, scale folded
    const unsigned short* __restrict__ XbT,  // [32][256][768] bf16
    bf16* __restrict__ Q, bf16* __restrict__ K, bf16* __restrict__ Vt)
{
    const int n0 = blockIdx.x * 64;
    const int g  = blockIdx.y;
    const int b  = blockIdx.z;
    const int bs = b >> 4, fr = b & 15;
    const int qkv = g / 12, head = g % 12;
    const int m0 = g * 64;

    const int tid = threadIdx.x;
    const int w = tid >> 6, lane = tid & 63;
    const int l15 = lane & 15, quad = lane >> 4;

    __shared__ unsigned short Bs[64 * 72];

    const unsigned short* Arow = Wqb + (size_t)m0 * 768;
    const unsigned short* Bsrc = XbT + ((size_t)b * 256 + n0) * 768;

    f32x4 acc[4];
    #pragma unroll
    for (int mi = 0; mi < 4; mi++) acc[mi] = (f32x4){0.f, 0.f, 0.f, 0.f};

    const int srow = tid >> 2, soff = (tid & 3) * 16;

    for (int k0 = 0; k0 < 768; k0 += 64) {
        short8 af[4][2];
        #pragma unroll
        for (int mi = 0; mi < 4; mi++)
            #pragma unroll
            for (int kk = 0; kk < 2; kk++)
                af[mi][kk] = *(const short8*)&Arow[(size_t)(16 * mi + l15) * 768 + k0 + 32 * kk + 8 * quad];
        const short8 s0 = *(const short8*)&Bsrc[(size_t)srow * 768 + k0 + soff];
        const short8 s1 = *(const short8*)&Bsrc[(size_t)srow * 768 + k0 + soff + 8];
        __syncthreads();
        *(short8*)&Bs[srow * 72 + soff] = s0;
        *(short8*)&Bs[srow * 72 + soff + 8] = s1;
        __syncthreads();
        #pragma unroll
        for (int kk = 0; kk < 2; kk++) {
            const short8 bfrag = *(const short8*)&Bs[(16 * w + l15) * 72 + 32 * kk + 8 * quad];
            #pragma unroll
            for (int mi = 0; mi < 4; mi++)
                acc[mi] = __builtin_amdgcn_mfma_f32_16x16x32_bf16(af[mi][kk], bfrag, acc[mi], 0, 0, 0);
        }
    }

    float ssq = 0.f;
    #pragma unroll
    for (int mi = 0; mi < 4; mi++)
        #pragma unroll
        for (int r = 0; r < 4; r++)
            ssq = fmaf(acc[mi][r], acc[mi][r], ssq);
    ssq += __shfl_xor(ssq, 16, 64);
    ssq += __shfl_xor(ssq, 32, 64);
    const float inv = 1.0f / (EPSV + sqrtf(ssq) * 0.125f);

    const int token = fr * 256 + n0 + 16 * w + l15;

    if (qkv == 2) {
        const size_t vbase = ((size_t)(bs * 12 + head) * 64) * 4096 + token;
        #pragma unroll
        for (int mi = 0; mi < 4; mi++)
            #pragma unroll
            for (int r = 0; r < 4; r++)
                Vt[vbase + (size_t)(16 * mi + 4 * quad + r) * 4096] =
                    __float2bfloat16(acc[mi][r] * inv);
    } else {
        unsigned short* dst = (unsigned short*)((qkv == 0) ? Q : K);
        const float post = (qkv == 0) ? 0.125f : 1.0f;  // fold 1/sqrt(c) into Q
        const size_t base = (((size_t)(bs * 12 + head)) * 4096 + token) * 64;
        #pragma unroll
        for (int mi = 0; mi < 2; mi++) {
            unsigned int lo[2], hi[2];
            #pragma unroll
            for (int r = 0; r < 4; r++) {
                const int j = 16 * mi + 4 * quad + r;
                const float n1 = acc[mi][r] * inv;
                const float n2 = acc[mi + 2][r] * inv;
                const float ang = (float)fr * exp2f(-(float)j * 0.41524101186092029f);
                float sn, cs;
                __sincosf(ang, &sn, &cs);
                const unsigned short o1 = f2bf((n1 * cs - n2 * sn) * post);
                const unsigned short o2 = f2bf((n2 * cs + n1 * sn) * post);
                if (r < 2) { if (r == 0) { lo[0] = o1; hi[0] = o2; } else { lo[0] |= (unsigned int)o1 << 16; hi[0] |= (unsigned int)o2 << 16; } }
                else       { if (r == 2) { lo[1] = o1; hi[1] = o2; } else { lo[1] |= (unsigned int)o1 << 16; hi[1] |= (unsigned int)o2 << 16; } }
            }
            *(uint2*)&dst[base + 16 * mi + 4 * quad]      = make_uint2(lo[0], lo[1]);
            *(uint2*)&dst[base + 32 + 16 * mi + 4 * quad] = make_uint2(hi[0], hi[1]);
        }
    }
}

// ---------------------------------------------------------------------------
// Kernel 4: MFMA flash attention, frame-causal. Fine-grained grid:
// block = (64-query tile, head, bs) -> 1536 blocks (was 384). Wave owns 16
// queries. Heavy tiles (late frames) dispatch first. LDS 27.6 KB.
// ---------------------------------------------------------------------------
__global__ __launch_bounds__(256, 4) void attn_mfma_kernel(
    const bf16* __restrict__ Qg, const bf16* __restrict__ Kg,
    const bf16* __restrict__ Vtg, unsigned short* __restrict__ OspT)
{
    const int qtile = 63 - blockIdx.x;           // heavy first
    const int qfr = qtile >> 2;                  // frame of this query tile
    const int head = blockIdx.y, bs = blockIdx.z;
    const int tid = threadIdx.x;
    const int w = tid >> 6, lane = tid & 63;
    const int l15 = lane & 15, quad = lane >> 4;
    const size_t hb = ((size_t)(bs * 12 + head)) * 4096 * 64;

    __shared__ unsigned short Ks[64 * 72];
    __shared__ unsigned short Vs[64 * 72];
    __shared__ unsigned short Pw[4][16 * 72];

    const unsigned short* Qu = (const unsigned short*)Qg;
    const unsigned short* Ku = (const unsigned short*)Kg;
    const unsigned short* Vu = (const unsigned short*)Vtg;

    // wave w owns queries (qtile&3)*64 + w*16 + l15 within the frame
    short8 Qf[2];
    {
        const int qrow = qfr * 256 + (qtile & 3) * 64 + w * 16 + l15;
        #pragma unroll
        for (int kk = 0; kk < 2; kk++)
            Qf[kk] = *(const short8*)&Qu[hb + (size_t)qrow * 64 + 32 * kk + 8 * quad];
    }

    f32x4 O[4];
    #pragma unroll
    for (int c = 0; c < 4; c++) O[c] = (f32x4){0.f, 0.f, 0.f, 0.f};
    float lsum = 0.f;
    const f32x4 zf = (f32x4){0.f, 0.f, 0.f, 0.f};

    const int stage_row = tid >> 2;
    const int stage_off = (tid & 3) * 16;

    const int nk = (qfr + 1) * 256;
    for (int t0 = 0; t0 < nk; t0 += 64) {
        __syncthreads();
        {
            const size_t kg = hb + (size_t)(t0 + stage_row) * 64 + stage_off;
            const size_t vg = hb + (size_t)stage_row * 4096 + t0 + stage_off;
            const short8 ka = *(const short8*)&Ku[kg];
            const short8 kb = *(const short8*)&Ku[kg + 8];
            const short8 va = *(const short8*)&Vu[vg];
            const short8 vb = *(const short8*)&Vu[vg + 8];
            *(short8*)&Ks[stage_row * 72 + stage_off] = ka;
            *(short8*)&Ks[stage_row * 72 + stage_off + 8] = kb;
            *(short8*)&Vs[stage_row * 72 + stage_off] = va;
            *(short8*)&Vs[stage_row * 72 + stage_off + 8] = vb;
        }
        __syncthreads();

        // S^T[key][query] = K · Q^T : lane holds query l15, keys 16mi+4quad+r
        f32x4 St[4];
        #pragma unroll
        for (int mi = 0; mi < 4; mi++) {
            const short8 kf0 = *(const short8*)&Ks[(16 * mi + l15) * 72 + 8 * quad];
            const short8 kf1 = *(const short8*)&Ks[(16 * mi + l15) * 72 + 32 + 8 * quad];
            f32x4 s = __builtin_amdgcn_mfma_f32_16x16x32_bf16(kf0, Qf[0], zf, 0, 0, 0);
            St[mi] = __builtin_amdgcn_mfma_f32_16x16x32_bf16(kf1, Qf[1], s, 0, 0, 0);
        }

        // P = exp(S - 8), pack to LDS key-contiguous per query row
        #pragma unroll
        for (int mi = 0; mi < 4; mi++) {
            const f32x4 s = St[mi];
            const float p0 = __expf(s[0] - 8.f);
            const float p1 = __expf(s[1] - 8.f);
            const float p2 = __expf(s[2] - 8.f);
            const float p3 = __expf(s[3] - 8.f);
            lsum += (p0 + p1) + (p2 + p3);
            uint2 d;
            d.x = (unsigned int)f2bf(p0) | ((unsigned int)f2bf(p1) << 16);
            d.y = (unsigned int)f2bf(p2) | ((unsigned int)f2bf(p3) << 16);
            *(uint2*)&Pw[w][l15 * 72 + 16 * mi + 4 * quad] = d;
        }

        // PV: O[q][c] += P·V
        short8 Pf[2];
        #pragma unroll
        for (int ks = 0; ks < 2; ks++)
            Pf[ks] = *(const short8*)&Pw[w][l15 * 72 + 32 * ks + 8 * quad];
        #pragma unroll
        for (int ci = 0; ci < 4; ci++) {
            const short8 vf0 = *(const short8*)&Vs[(16 * ci + l15) * 72 + 8 * quad];
            const short8 vf1 = *(const short8*)&Vs[(16 * ci + l15) * 72 + 32 + 8 * quad];
            O[ci] = __builtin_amdgcn_mfma_f32_16x16x32_bf16(Pf[0], vf0, O[ci], 0, 0, 0);
            O[ci] = __builtin_amdgcn_mfma_f32_16x16x32_bf16(Pf[1], vf1, O[ci], 0, 0, 0);
        }
    }

    lsum += __shfl_xor(lsum, 16, 64);
    lsum += __shfl_xor(lsum, 32, 64);
    lsum = 1.0f / lsum;

    // O: row(query within 16) = 4quad+r, col(channel) = 16ci+l15
    const size_t ob = ((size_t)(bs * 16 + qfr)) * 196608;   // 256*768
    #pragma unroll
    for (int r = 0; r < 4; r++) {
        const float inv = __shfl(lsum, quad * 4 + r, 64);
        const int pos = (qtile & 3) * 64 + w * 16 + 4 * quad + r;
        #pragma unroll
        for (int ci = 0; ci < 4; ci++) {
            const int chan = (16 * ci + l15) * 12 + head;
            OspT[ob + (size_t)pos * 768 + chan] = f2bf(O[ci][r] * inv);
        }
    }
}

// ---------------------------------------------------------------------------
// Kernel 5: projection GEMM (MFMA bf16) + residual mix epilogue (fp32 out).
// ---------------------------------------------------------------------------
__global__ __launch_bounds__(256) void proj_mfma_kernel(
    const unsigned short* __restrict__ Wpb,   // [768][768] bf16, scale folded
    const unsigned short* __restrict__ OspT,  // [32][256][768] bf16
    const float* __restrict__ X,
    float* __restrict__ Out)
{
    const int n0 = blockIdx.x * 64;
    const int m0 = blockIdx.y * 64;
    const int b  = blockIdx.z;

    const int tid = threadIdx.x;
    const int w = tid >> 6, lane = tid & 63;
    const int l15 = lane & 15, quad = lane >> 4;

    __shared__ unsigned short Bs[64 * 72];

    const unsigned short* Arow = Wpb + (size_t)m0 * 768;
    const unsigned short* Bsrc = OspT + ((size_t)b * 256 + n0) * 768;

    f32x4 acc[4];
    #pragma unroll
    for (int mi = 0; mi < 4; mi++) acc[mi] = (f32x4){0.f, 0.f, 0.f, 0.f};

    const int srow = tid >> 2, soff = (tid & 3) * 16;

    for (int k0 = 0; k0 < 768; k0 += 64) {
        short8 af[4][2];
        #pragma unroll
        for (int mi = 0; mi < 4; mi++)
            #pragma unroll
            for (int kk = 0; kk < 2; kk++)
                af[mi][kk] = *(const short8*)&Arow[(size_t)(16 * mi + l15) * 768 + k0 + 32 * kk + 8 * quad];
        const short8 s0 = *(const short8*)&Bsrc[(size_t)srow * 768 + k0 + soff];
        const short8 s1 = *(const short8*)&Bsrc[(size_t)srow * 768 + k0 + soff + 8];
        __syncthreads();
        *(short8*)&Bs[srow * 72 + soff] = s0;
        *(short8*)&Bs[srow * 72 + soff + 8] = s1;
        __syncthreads();
        #pragma unroll
        for (int kk = 0; kk < 2; kk++) {
            const short8 bfrag = *(const short8*)&Bs[(16 * w + l15) * 72 + 32 * kk + 8 * quad];
            #pragma unroll
            for (int mi = 0; mi < 4; mi++)
                acc[mi] = __builtin_amdgcn_mfma_f32_16x16x32_bf16(af[mi][kk], bfrag, acc[mi], 0, 0, 0);
        }
    }

    const float kMix = 1.3130643285972254f; // 1/sqrt(0.58)
    const int n = n0 + 16 * w + l15;
    #pragma unroll
    for (int mi = 0; mi < 4; mi++) {
        #pragma unroll
        for (int r = 0; r < 4; r++) {
            const int m = m0 + 16 * mi + 4 * quad + r;
            const size_t idx = (size_t)b * 196608 + (size_t)m * 256 + n;
            Out[idx] = (0.7f * X[idx] + 0.3f * acc[mi][r]) * kMix;
        }
    }
}

// ---------------------------------------------------------------------------
extern "C" void kernel_launch(void* const* d_in, const int* in_sizes, int n_in,
                              void* d_out, int out_size, void* d_ws, size_t ws_size,
                              hipStream_t stream) {
    const float* x     = (const float*)d_in[0];
    const float* wqkv  = (const float*)d_in[1];
    const float* wproj = (const float*)d_in[2];
    float* out = (float*)d_out;

    // workspace layout (~55 MB). OspT aliases XbT (dead after qkv_mfma).
    char* ws = (char*)d_ws;
    unsigned short* Wqb  = (unsigned short*)(ws + 0);          //  3,538,944 B
    unsigned short* Wpb  = (unsigned short*)(ws + 3538944);    //  1,179,648 B
    unsigned short* XbT  = (unsigned short*)(ws + 4718592);    // 12,582,912 B
    unsigned short* OspT = XbT;                                // alias
    bf16*  Q   = (bf16*)(ws + 17301504);                       // 12,582,912 B
    bf16*  K   = (bf16*)(ws + 29884416);                       // 12,582,912 B
    bf16*  Vt  = (bf16*)(ws + 42467328);                       // 12,582,912 B -> 55,050,240

    rownorm_cast_kernel<<<3072, 256, 0, stream>>>(wqkv, wproj, Wqb, Wpb);
    cast_x_kernel<<<dim3(12, 32), 256, 0, stream>>>(x, XbT);
    qkv_mfma_kernel<<<dim3(4, 36, 32), 256, 0, stream>>>(Wqb, XbT, Q, K, Vt);
    attn_mfma_kernel<<<dim3(64, 12, 2), 256, 0, stream>>>(Q, K, Vt, OspT);
    proj_mfma_kernel<<<dim3(4, 12, 32), 256, 0, stream>>>(Wpb, OspT, x, out);
}

// Round 7
// 314.945 us; speedup vs baseline: 20.7840x; 1.6205x over previous
//
#include <hip/hip_runtime.h>
#include <hip/hip_bf16.h>
#include <math.h>

typedef __hip_bfloat16 bf16;
typedef __attribute__((ext_vector_type(8))) short short8;
typedef __attribute__((ext_vector_type(4))) float f32x4;

#define EPSV 0.0001f

__device__ __forceinline__ unsigned short f2bf(float f) {  // RNE bf16 bits
    unsigned int u = __float_as_uint(f);
    u += 0x7fff + ((u >> 16) & 1);
    return (unsigned short)(u >> 16);
}

// ---------------------------------------------------------------------------
// Kernel 1: weight row-norm + cast to bf16 with scale folded in.
// ---------------------------------------------------------------------------
__global__ __launch_bounds__(256) void rownorm_cast_kernel(
    const float* __restrict__ w_qkv, const float* __restrict__ w_proj,
    unsigned short* __restrict__ Wqb, unsigned short* __restrict__ Wpb)
{
    const int row = blockIdx.x;
    const float* src;
    unsigned short* dst;
    if (row < 2304) { src = w_qkv + (size_t)row * 768;           dst = Wqb + (size_t)row * 768; }
    else            { src = w_proj + (size_t)(row - 2304) * 768; dst = Wpb + (size_t)(row - 2304) * 768; }

    const int tid = threadIdx.x;
    float v[3];
    float ss = 0.f;
    #pragma unroll
    for (int j = 0; j < 3; j++) {
        v[j] = src[tid + j * 256];
        ss += v[j] * v[j];
    }
    #pragma unroll
    for (int off = 32; off > 0; off >>= 1) ss += __shfl_down(ss, off, 64);
    __shared__ float wsum[4];
    if ((tid & 63) == 0) wsum[tid >> 6] = ss;
    __syncthreads();
    const float total = wsum[0] + wsum[1] + wsum[2] + wsum[3];
    const float scale = 1.0f / (EPSV * 27.712812921102035f + sqrtf(total)); // sqrt(768)
    #pragma unroll
    for (int j = 0; j < 3; j++) dst[tid + j * 256] = f2bf(v[j] * scale);
}

// ---------------------------------------------------------------------------
// Kernel 2: X [32][768][256] fp32 -> XbT [32][256][768] bf16 (transposed).
// ---------------------------------------------------------------------------
__global__ __launch_bounds__(256) void cast_x_kernel(
    const float* __restrict__ X, unsigned short* __restrict__ XbT)
{
    const int c0 = blockIdx.x * 64;
    const int b  = blockIdx.y;
    const int pos = threadIdx.x;
    const float* src = X + ((size_t)b * 768 + c0) * 256 + pos;
    unsigned short* dst = XbT + ((size_t)b * 256 + pos) * 768 + c0;
    #pragma unroll
    for (int cc = 0; cc < 8; cc++) {
        short8 t;
        #pragma unroll
        for (int j = 0; j < 8; j++)
            t[j] = (short)f2bf(src[(size_t)(cc * 8 + j) * 256]);
        *(short8*)&dst[cc * 8] = t;
    }
}

// ---------------------------------------------------------------------------
// Kernel 3: QKV GEMM (MFMA bf16), wide tile: block = 64 weight-rows x 256
// positions, 4 waves each own 64x64. A and B staged coalesced through LDS
// (stride-72 padding: 2-way bank aliasing only). Fused in-register
// normalize + RoPE epilogue; V bounced through LDS for coalesced stores.
// ---------------------------------------------------------------------------
__global__ __launch_bounds__(256, 2) void qkv_mfma_kernel(
    const unsigned short* __restrict__ Wqb,  // [2304][768] bf16, scale folded
    const unsigned short* __restrict__ XbT,  // [32][256][768] bf16
    bf16* __restrict__ Q, bf16* __restrict__ K, bf16* __restrict__ Vt)
{
    const int g = blockIdx.x;            // 0..35 (= qkv*12 + head)
    const int b = blockIdx.y;            // 0..31 (= bs*16 + fr)
    const int bs = b >> 4, fr = b & 15;
    const int qkv = g / 12, head = g % 12;
    const int m0 = g * 64;

    const int tid = threadIdx.x;
    const int w = tid >> 6, lane = tid & 63;
    const int l15 = lane & 15, quad = lane >> 4;

    __shared__ unsigned short As[64 * 72];    //  9.2 KB
    __shared__ unsigned short Bs[256 * 72];   // 36.9 KB

    const unsigned short* Ag = Wqb + (size_t)m0 * 768;
    const unsigned short* Bg = XbT + (size_t)b * 256 * 768;

    f32x4 acc[4][4];   // [mi][ni]
    #pragma unroll
    for (int mi = 0; mi < 4; mi++)
        #pragma unroll
        for (int ni = 0; ni < 4; ni++)
            acc[mi][ni] = (f32x4){0.f, 0.f, 0.f, 0.f};

    const int arow = tid >> 2, acol = (tid & 3) * 16;   // A: 4 thr/row, 32 B each
    const int brow = tid >> 3, bcol = (tid & 7) * 8;    // B: 8 thr/row, 16 B each

    for (int k0 = 0; k0 < 768; k0 += 64) {
        const short8 av0 = *(const short8*)&Ag[(size_t)arow * 768 + k0 + acol];
        const short8 av1 = *(const short8*)&Ag[(size_t)arow * 768 + k0 + acol + 8];
        short8 bv[8];
        #pragma unroll
        for (int p = 0; p < 8; p++)
            bv[p] = *(const short8*)&Bg[(size_t)(32 * p + brow) * 768 + k0 + bcol];
        __syncthreads();
        *(short8*)&As[arow * 72 + acol] = av0;
        *(short8*)&As[arow * 72 + acol + 8] = av1;
        #pragma unroll
        for (int p = 0; p < 8; p++)
            *(short8*)&Bs[(32 * p + brow) * 72 + bcol] = bv[p];
        __syncthreads();

        short8 af[4][2], bfr[4][2];
        #pragma unroll
        for (int mi = 0; mi < 4; mi++)
            #pragma unroll
            for (int kk = 0; kk < 2; kk++)
                af[mi][kk] = *(const short8*)&As[(16 * mi + l15) * 72 + 32 * kk + 8 * quad];
        #pragma unroll
        for (int ni = 0; ni < 4; ni++)
            #pragma unroll
            for (int kk = 0; kk < 2; kk++)
                bfr[ni][kk] = *(const short8*)&Bs[(64 * w + 16 * ni + l15) * 72 + 32 * kk + 8 * quad];
        #pragma unroll
        for (int kk = 0; kk < 2; kk++)
            #pragma unroll
            for (int mi = 0; mi < 4; mi++)
                #pragma unroll
                for (int ni = 0; ni < 4; ni++)
                    acc[mi][ni] = __builtin_amdgcn_mfma_f32_16x16x32_bf16(af[mi][kk], bfr[ni][kk], acc[mi][ni], 0, 0, 0);
    }

    // per-position normalization over the 64 channels (rows) of this head
    float inv[4];
    #pragma unroll
    for (int ni = 0; ni < 4; ni++) {
        float ssq = 0.f;
        #pragma unroll
        for (int mi = 0; mi < 4; mi++)
            #pragma unroll
            for (int r = 0; r < 4; r++)
                ssq = fmaf(acc[mi][ni][r], acc[mi][ni][r], ssq);
        ssq += __shfl_xor(ssq, 16, 64);
        ssq += __shfl_xor(ssq, 32, 64);
        inv[ni] = 1.0f / (EPSV + sqrtf(ssq) * 0.125f);
    }

    if (qkv == 2) {
        // bounce through own Bs slice ([pos][ch], stride 72) for coalesced stores
        unsigned short* Vb = &Bs[w * 64 * 72];
        #pragma unroll
        for (int ni = 0; ni < 4; ni++)
            #pragma unroll
            for (int mi = 0; mi < 4; mi++) {
                uint2 d;
                d.x = (unsigned int)f2bf(acc[mi][ni][0] * inv[ni]) |
                      ((unsigned int)f2bf(acc[mi][ni][1] * inv[ni]) << 16);
                d.y = (unsigned int)f2bf(acc[mi][ni][2] * inv[ni]) |
                      ((unsigned int)f2bf(acc[mi][ni][3] * inv[ni]) << 16);
                *(uint2*)&Vb[(16 * ni + l15) * 72 + 16 * mi + 4 * quad] = d;
            }
        unsigned short* Vtu = (unsigned short*)Vt;
        const size_t cb = ((size_t)(bs * 12 + head) * 64);
        const int tok = fr * 256 + 64 * w + lane;
        #pragma unroll 8
        for (int ch = 0; ch < 64; ch++)
            Vtu[(cb + ch) * 4096 + tok] = Vb[lane * 72 + ch];
    } else {
        unsigned short* dst = (unsigned short*)((qkv == 0) ? Q : K);
        const float post = (qkv == 0) ? 0.125f : 1.0f;   // fold 1/sqrt(c) into Q
        #pragma unroll
        for (int ni = 0; ni < 4; ni++) {
            const int token = fr * 256 + 64 * w + 16 * ni + l15;
            const size_t base = (((size_t)(bs * 12 + head)) * 4096 + token) * 64;
            #pragma unroll
            for (int mi = 0; mi < 2; mi++) {
                unsigned int lo[2], hi[2];
                #pragma unroll
                for (int r = 0; r < 4; r++) {
                    const int j = 16 * mi + 4 * quad + r;
                    const float n1 = acc[mi][ni][r] * inv[ni];
                    const float n2 = acc[mi + 2][ni][r] * inv[ni];
                    const float ang = (float)fr * exp2f(-(float)j * 0.41524101186092029f);
                    float sn, cs;
                    __sincosf(ang, &sn, &cs);
                    const unsigned short o1 = f2bf((n1 * cs - n2 * sn) * post);
                    const unsigned short o2 = f2bf((n2 * cs + n1 * sn) * post);
                    if (r < 2) { if (r == 0) { lo[0] = o1; hi[0] = o2; } else { lo[0] |= (unsigned int)o1 << 16; hi[0] |= (unsigned int)o2 << 16; } }
                    else       { if (r == 2) { lo[1] = o1; hi[1] = o2; } else { lo[1] |= (unsigned int)o1 << 16; hi[1] |= (unsigned int)o2 << 16; } }
                }
                *(uint2*)&dst[base + 16 * mi + 4 * quad]      = make_uint2(lo[0], lo[1]);
                *(uint2*)&dst[base + 32 + 16 * mi + 4 * quad] = make_uint2(hi[0], hi[1]);
            }
        }
    }
}

// ---------------------------------------------------------------------------
// Kernel 4: MFMA flash attention, frame-causal (round-5 split version).
// ---------------------------------------------------------------------------
__global__ __launch_bounds__(256, 4) void attn_mfma_kernel(
    const bf16* __restrict__ Qg, const bf16* __restrict__ Kg,
    const bf16* __restrict__ Vtg, unsigned short* __restrict__ OspT)
{
    const int qtile = 63 - blockIdx.x;           // heavy first
    const int qfr = qtile >> 2;
    const int head = blockIdx.y, bs = blockIdx.z;
    const int tid = threadIdx.x;
    const int w = tid >> 6, lane = tid & 63;
    const int l15 = lane & 15, quad = lane >> 4;
    const size_t hb = ((size_t)(bs * 12 + head)) * 4096 * 64;

    __shared__ unsigned short Ks[64 * 72];
    __shared__ unsigned short Vs[64 * 72];
    __shared__ unsigned short Pw[4][16 * 72];

    const unsigned short* Qu = (const unsigned short*)Qg;
    const unsigned short* Ku = (const unsigned short*)Kg;
    const unsigned short* Vu = (const unsigned short*)Vtg;

    short8 Qf[2];
    {
        const int qrow = qfr * 256 + (qtile & 3) * 64 + w * 16 + l15;
        #pragma unroll
        for (int kk = 0; kk < 2; kk++)
            Qf[kk] = *(const short8*)&Qu[hb + (size_t)qrow * 64 + 32 * kk + 8 * quad];
    }

    f32x4 O[4];
    #pragma unroll
    for (int c = 0; c < 4; c++) O[c] = (f32x4){0.f, 0.f, 0.f, 0.f};
    float lsum = 0.f;
    const f32x4 zf = (f32x4){0.f, 0.f, 0.f, 0.f};

    const int stage_row = tid >> 2;
    const int stage_off = (tid & 3) * 16;

    const int nk = (qfr + 1) * 256;
    for (int t0 = 0; t0 < nk; t0 += 64) {
        __syncthreads();
        {
            const size_t kg = hb + (size_t)(t0 + stage_row) * 64 + stage_off;
            const size_t vg = hb + (size_t)stage_row * 4096 + t0 + stage_off;
            const short8 ka = *(const short8*)&Ku[kg];
            const short8 kb = *(const short8*)&Ku[kg + 8];
            const short8 va = *(const short8*)&Vu[vg];
            const short8 vb = *(const short8*)&Vu[vg + 8];
            *(short8*)&Ks[stage_row * 72 + stage_off] = ka;
            *(short8*)&Ks[stage_row * 72 + stage_off + 8] = kb;
            *(short8*)&Vs[stage_row * 72 + stage_off] = va;
            *(short8*)&Vs[stage_row * 72 + stage_off + 8] = vb;
        }
        __syncthreads();

        f32x4 St[4];
        #pragma unroll
        for (int mi = 0; mi < 4; mi++) {
            const short8 kf0 = *(const short8*)&Ks[(16 * mi + l15) * 72 + 8 * quad];
            const short8 kf1 = *(const short8*)&Ks[(16 * mi + l15) * 72 + 32 + 8 * quad];
            f32x4 s = __builtin_amdgcn_mfma_f32_16x16x32_bf16(kf0, Qf[0], zf, 0, 0, 0);
            St[mi] = __builtin_amdgcn_mfma_f32_16x16x32_bf16(kf1, Qf[1], s, 0, 0, 0);
        }

        #pragma unroll
        for (int mi = 0; mi < 4; mi++) {
            const f32x4 s = St[mi];
            const float p0 = __expf(s[0] - 8.f);
            const float p1 = __expf(s[1] - 8.f);
            const float p2 = __expf(s[2] - 8.f);
            const float p3 = __expf(s[3] - 8.f);
            lsum += (p0 + p1) + (p2 + p3);
            uint2 d;
            d.x = (unsigned int)f2bf(p0) | ((unsigned int)f2bf(p1) << 16);
            d.y = (unsigned int)f2bf(p2) | ((unsigned int)f2bf(p3) << 16);
            *(uint2*)&Pw[w][l15 * 72 + 16 * mi + 4 * quad] = d;
        }

        short8 Pf[2];
        #pragma unroll
        for (int ks = 0; ks < 2; ks++)
            Pf[ks] = *(const short8*)&Pw[w][l15 * 72 + 32 * ks + 8 * quad];
        #pragma unroll
        for (int ci = 0; ci < 4; ci++) {
            const short8 vf0 = *(const short8*)&Vs[(16 * ci + l15) * 72 + 8 * quad];
            const short8 vf1 = *(const short8*)&Vs[(16 * ci + l15) * 72 + 32 + 8 * quad];
            O[ci] = __builtin_amdgcn_mfma_f32_16x16x32_bf16(Pf[0], vf0, O[ci], 0, 0, 0);
            O[ci] = __builtin_amdgcn_mfma_f32_16x16x32_bf16(Pf[1], vf1, O[ci], 0, 0, 0);
        }
    }

    lsum += __shfl_xor(lsum, 16, 64);
    lsum += __shfl_xor(lsum, 32, 64);
    lsum = 1.0f / lsum;

    const size_t ob = ((size_t)(bs * 16 + qfr)) * 196608;   // 256*768
    #pragma unroll
    for (int r = 0; r < 4; r++) {
        const float inv = __shfl(lsum, quad * 4 + r, 64);
        const int pos = (qtile & 3) * 64 + w * 16 + 4 * quad + r;
        #pragma unroll
        for (int ci = 0; ci < 4; ci++) {
            const int chan = (16 * ci + l15) * 12 + head;
            OspT[ob + (size_t)pos * 768 + chan] = f2bf(O[ci][r] * inv);
        }
    }
}

// ---------------------------------------------------------------------------
// Kernel 5: projection GEMM (MFMA bf16), wide tile, + residual mix epilogue.
// ---------------------------------------------------------------------------
__global__ __launch_bounds__(256, 2) void proj_mfma_kernel(
    const unsigned short* __restrict__ Wpb,   // [768][768] bf16, scale folded
    const unsigned short* __restrict__ OspT,  // [32][256][768] bf16
    const float* __restrict__ X,
    float* __restrict__ Out)
{
    const int my = blockIdx.x;           // 0..11
    const int b  = blockIdx.y;           // 0..31
    const int m0 = my * 64;

    const int tid = threadIdx.x;
    const int w = tid >> 6, lane = tid & 63;
    const int l15 = lane & 15, quad = lane >> 4;

    __shared__ unsigned short As[64 * 72];
    __shared__ unsigned short Bs[256 * 72];

    const unsigned short* Ag = Wpb + (size_t)m0 * 768;
    const unsigned short* Bg = OspT + (size_t)b * 256 * 768;

    f32x4 acc[4][4];
    #pragma unroll
    for (int mi = 0; mi < 4; mi++)
        #pragma unroll
        for (int ni = 0; ni < 4; ni++)
            acc[mi][ni] = (f32x4){0.f, 0.f, 0.f, 0.f};

    const int arow = tid >> 2, acol = (tid & 3) * 16;
    const int brow = tid >> 3, bcol = (tid & 7) * 8;

    for (int k0 = 0; k0 < 768; k0 += 64) {
        const short8 av0 = *(const short8*)&Ag[(size_t)arow * 768 + k0 + acol];
        const short8 av1 = *(const short8*)&Ag[(size_t)arow * 768 + k0 + acol + 8];
        short8 bv[8];
        #pragma unroll
        for (int p = 0; p < 8; p++)
            bv[p] = *(const short8*)&Bg[(size_t)(32 * p + brow) * 768 + k0 + bcol];
        __syncthreads();
        *(short8*)&As[arow * 72 + acol] = av0;
        *(short8*)&As[arow * 72 + acol + 8] = av1;
        #pragma unroll
        for (int p = 0; p < 8; p++)
            *(short8*)&Bs[(32 * p + brow) * 72 + bcol] = bv[p];
        __syncthreads();

        short8 af[4][2], bfr[4][2];
        #pragma unroll
        for (int mi = 0; mi < 4; mi++)
            #pragma unroll
            for (int kk = 0; kk < 2; kk++)
                af[mi][kk] = *(const short8*)&As[(16 * mi + l15) * 72 + 32 * kk + 8 * quad];
        #pragma unroll
        for (int ni = 0; ni < 4; ni++)
            #pragma unroll
            for (int kk = 0; kk < 2; kk++)
                bfr[ni][kk] = *(const short8*)&Bs[(64 * w + 16 * ni + l15) * 72 + 32 * kk + 8 * quad];
        #pragma unroll
        for (int kk = 0; kk < 2; kk++)
            #pragma unroll
            for (int mi = 0; mi < 4; mi++)
                #pragma unroll
                for (int ni = 0; ni < 4; ni++)
                    acc[mi][ni] = __builtin_amdgcn_mfma_f32_16x16x32_bf16(af[mi][kk], bfr[ni][kk], acc[mi][ni], 0, 0, 0);
    }

    const float kMix = 1.3130643285972254f; // 1/sqrt(0.58)
    #pragma unroll
    for (int mi = 0; mi < 4; mi++)
        #pragma unroll
        for (int r = 0; r < 4; r++) {
            const int m = m0 + 16 * mi + 4 * quad + r;
            const size_t rowb = (size_t)b * 196608 + (size_t)m * 256;
            #pragma unroll
            for (int ni = 0; ni < 4; ni++) {
                const int n = 64 * w + 16 * ni + l15;
                Out[rowb + n] = (0.7f * X[rowb + n] + 0.3f * acc[mi][ni][r]) * kMix;
            }
        }
}

// ---------------------------------------------------------------------------
extern "C" void kernel_launch(void* const* d_in, const int* in_sizes, int n_in,
                              void* d_out, int out_size, void* d_ws, size_t ws_size,
                              hipStream_t stream) {
    const float* x     = (const float*)d_in[0];
    const float* wqkv  = (const float*)d_in[1];
    const float* wproj = (const float*)d_in[2];
    float* out = (float*)d_out;

    // workspace layout (~55 MB). OspT aliases XbT (dead after qkv_mfma).
    char* ws = (char*)d_ws;
    unsigned short* Wqb  = (unsigned short*)(ws + 0);          //  3,538,944 B
    unsigned short* Wpb  = (unsigned short*)(ws + 3538944);    //  1,179,648 B
    unsigned short* XbT  = (unsigned short*)(ws + 4718592);    // 12,582,912 B
    unsigned short* OspT = XbT;                                // alias
    bf16*  Q   = (bf16*)(ws + 17301504);                       // 12,582,912 B
    bf16*  K   = (bf16*)(ws + 29884416);                       // 12,582,912 B
    bf16*  Vt  = (bf16*)(ws + 42467328);                       // 12,582,912 B -> 55,050,240

    rownorm_cast_kernel<<<3072, 256, 0, stream>>>(wqkv, wproj, Wqb, Wpb);
    cast_x_kernel<<<dim3(12, 32), 256, 0, stream>>>(x, XbT);
    qkv_mfma_kernel<<<dim3(36, 32), 256, 0, stream>>>(Wqb, XbT, Q, K, Vt);
    attn_mfma_kernel<<<dim3(64, 12, 2), 256, 0, stream>>>(Q, K, Vt, OspT);
    proj_mfma_kernel<<<dim3(12, 32), 256, 0, stream>>>(Wpb, OspT, x, out);
}